// Round 7
// baseline (416.350 us; speedup 1.0000x reference)
//
#include <hip/hip_runtime.h>
#include <stdint.h>

typedef uint32_t u32;
typedef uint16_t u16;

static constexpr int M_DIM = 8192;
static constexpr int N_DIM = 1024;
static constexpr int K_DIM = 4096;

// ws layout: H row-major fp16 [8192][4096] (64 MiB) + Wt frag-major (8 MiB)
static constexpr size_t H_BYTES  = (size_t)M_DIM * K_DIM * 2;   // 64 MiB
static constexpr size_t FRAG_U16 = 512;
static constexpr size_t WT_BYTES = 64ull * 128 * FRAG_U16 * 2;  // 8 MiB
static constexpr size_t WS_NEEDED = H_BYTES + WT_BYTES;         // 72 MiB

typedef __attribute__((ext_vector_type(8))) _Float16 half8;  // MFMA A/B frag (4 VGPRs)
typedef __attribute__((ext_vector_type(4))) float f32x4;     // MFMA C/D frag

__device__ __forceinline__ u32 pack2(float a, float b) {
  union { _Float16 h[2]; u32 u; } p;
  p.h[0] = (_Float16)a;   // v_cvt_f16_f32, RNE
  p.h[1] = (_Float16)b;
  return p.u;
}

// GELU via Abramowitz-Stegun 7.1.26 erf (|err| <= 1.5e-7) + dropout keep-mask * 1/(1-0.1).
__device__ __forceinline__ float gelu_drop(float x, u32 keep) {
  float ax = fabsf(x);
  float z  = ax * 0.70710678f;
  float t  = __builtin_amdgcn_rcpf(fmaf(0.3275911f, z, 1.0f));
  float poly = fmaf(fmaf(fmaf(fmaf(1.061405429f, t, -1.453152027f),
                              t, 1.421413741f),
                         t, -0.284496736f),
                    t, 0.254829592f) * t;
  float e   = exp2f(z * z * -1.44269504f);    // exp(-z^2)
  float erf = fmaf(-poly, e, 1.0f);           // erf(|x|/sqrt(2)) in [0,1)
  float g   = 0.5f * x * (1.0f + copysignf(erf, x));
  return keep ? g * 1.1111112f : 0.0f;
}

__device__ __forceinline__ void async_cp16(const void* g, void* l) {
  __builtin_amdgcn_global_load_lds((__attribute__((address_space(1))) u32*)g,
                                   (__attribute__((address_space(3))) u32*)l,
                                   16, 0, 0);
}

// ---------------- pass 1 (merged): W prepack + X gelu-pack to ROW-MAJOR H ----------------
// blocks [0, WPACK_BLOCKS): verified W prepack (17 MB f32 -> 8 MB fp16 frag-major).
// blocks [WPACK_BLOCKS, +PACKX_BLOCKS): pure streaming gelu pack, 16 elems/thread x 4 iters,
// 2-deep register pipeline; reads and writes fully contiguous (wave = 4 KB runs).
static constexpr int W_PAIRS = 64 * 64;
static constexpr int WPACK_BLOCKS = W_PAIRS / 4;    // 1024
static constexpr int PACKX_BLOCKS = 2048;
static constexpr size_t PACK_STR = 2048ull * 256 * 16;  // 8388608 elems per sweep

__global__ __launch_bounds__(256)
void pack_kernel(const float* __restrict__ X, const int* __restrict__ Mask,
                 const float* __restrict__ W, u16* __restrict__ H, u16* __restrict__ Wt) {
  if (blockIdx.x < WPACK_BLOCKS) {
    // ---- W prepack (verified R3-R5, unchanged) ----
    const int l     = threadIdx.x & 63;
    const int pj    = blockIdx.x * 4 + (threadIdx.x >> 6);
    const int row16 = l & 15;
    const int kof   = (l >> 4) << 4;
    const int fsub  = kof >> 5;
    const int q0    = (kof & 31) >> 3;
    const int nb = pj >> 6, kp = pj & 63;
    const float* wp = W + (size_t)(nb * 16 + row16) * K_DIM + kp * 64 + kof;
    float4 w0 = *(const float4*)(wp + 0);
    float4 w1 = *(const float4*)(wp + 4);
    float4 w2 = *(const float4*)(wp + 8);
    float4 w3 = *(const float4*)(wp + 12);
    const int f = kp * 2 + fsub;
    u16* dst = Wt + (size_t)(nb * 128 + f) * FRAG_U16 + (size_t)(row16 + 16 * q0) * 8;
    *(uint4*)(dst)       = make_uint4(pack2(w0.x, w0.y), pack2(w0.z, w0.w),
                                      pack2(w1.x, w1.y), pack2(w1.z, w1.w));
    *(uint4*)(dst + 128) = make_uint4(pack2(w2.x, w2.y), pack2(w2.z, w2.w),
                                      pack2(w3.x, w3.y), pack2(w3.z, w3.w));
    return;
  }

  const u32 t = (blockIdx.x - WPACK_BLOCKS) * 256 + threadIdx.x;  // 0..524287
  const float* xb = X    + (size_t)t * 16;
  const int*   mb = Mask + (size_t)t * 16;
  u16*         hb = H    + (size_t)t * 16;

  float4 xA0, xA1, xA2, xA3, xB0, xB1, xB2, xB3;
  uint4  mA0, mA1, mA2, mA3, mB0, mB1, mB2, mB3;

  auto loadA = [&](int it) {
    const float* p = xb + (size_t)it * PACK_STR;
    const int*   q = mb + (size_t)it * PACK_STR;
    xA0 = *(const float4*)(p + 0);  xA1 = *(const float4*)(p + 4);
    xA2 = *(const float4*)(p + 8);  xA3 = *(const float4*)(p + 12);
    mA0 = *(const uint4*)(q + 0);   mA1 = *(const uint4*)(q + 4);
    mA2 = *(const uint4*)(q + 8);   mA3 = *(const uint4*)(q + 12);
  };
  auto loadB = [&](int it) {
    const float* p = xb + (size_t)it * PACK_STR;
    const int*   q = mb + (size_t)it * PACK_STR;
    xB0 = *(const float4*)(p + 0);  xB1 = *(const float4*)(p + 4);
    xB2 = *(const float4*)(p + 8);  xB3 = *(const float4*)(p + 12);
    mB0 = *(const uint4*)(q + 0);   mB1 = *(const uint4*)(q + 4);
    mB2 = *(const uint4*)(q + 8);   mB3 = *(const uint4*)(q + 12);
  };
  auto procA = [&](int it) {
    u16* d = hb + (size_t)it * PACK_STR;
    *(uint4*)(d + 0) = make_uint4(
        pack2(gelu_drop(xA0.x, mA0.x), gelu_drop(xA0.y, mA0.y)),
        pack2(gelu_drop(xA0.z, mA0.z), gelu_drop(xA0.w, mA0.w)),
        pack2(gelu_drop(xA1.x, mA1.x), gelu_drop(xA1.y, mA1.y)),
        pack2(gelu_drop(xA1.z, mA1.z), gelu_drop(xA1.w, mA1.w)));
    *(uint4*)(d + 8) = make_uint4(
        pack2(gelu_drop(xA2.x, mA2.x), gelu_drop(xA2.y, mA2.y)),
        pack2(gelu_drop(xA2.z, mA2.z), gelu_drop(xA2.w, mA2.w)),
        pack2(gelu_drop(xA3.x, mA3.x), gelu_drop(xA3.y, mA3.y)),
        pack2(gelu_drop(xA3.z, mA3.z), gelu_drop(xA3.w, mA3.w)));
  };
  auto procB = [&](int it) {
    u16* d = hb + (size_t)it * PACK_STR;
    *(uint4*)(d + 0) = make_uint4(
        pack2(gelu_drop(xB0.x, mB0.x), gelu_drop(xB0.y, mB0.y)),
        pack2(gelu_drop(xB0.z, mB0.z), gelu_drop(xB0.w, mB0.w)),
        pack2(gelu_drop(xB1.x, mB1.x), gelu_drop(xB1.y, mB1.y)),
        pack2(gelu_drop(xB1.z, mB1.z), gelu_drop(xB1.w, mB1.w)));
    *(uint4*)(d + 8) = make_uint4(
        pack2(gelu_drop(xB2.x, mB2.x), gelu_drop(xB2.y, mB2.y)),
        pack2(gelu_drop(xB2.z, mB2.z), gelu_drop(xB2.w, mB2.w)),
        pack2(gelu_drop(xB3.x, mB3.x), gelu_drop(xB3.y, mB3.y)),
        pack2(gelu_drop(xB3.z, mB3.z), gelu_drop(xB3.w, mB3.w)));
  };

  // 4 sweeps, 2-deep pipeline
  loadA(0);
  loadB(1);
  procA(0);
  loadA(2);
  procB(1);
  loadB(3);
  procA(2);
  procB(3);
}

// ---------------- pass 2: 128x128 GEMM from H (row-major) + Wt (frag-major) ----------------
// m97 2-barrier single-buffer structure, 256 threads (4 waves, 2x2 of 64x64), 2 blocks/CU.
// A staged via global_load_lds with PRE-SWIZZLED source (m173): LDS dest linear, effective
// layout [row][k ^ ((row&7) slot)]; ds_read applies the same XOR -> conflict-free.
// B staged linear from frag-major Wt (verified R0 path). bn = bid&7 pins B panel per XCD.
__global__ __launch_bounds__(256, 2)
void gemm_kernel(const u16* __restrict__ H, const u16* __restrict__ Wt,
                 const float* __restrict__ Bias, float* __restrict__ Out) {
  __shared__ __attribute__((aligned(16))) u16 Asl[8192];  // 128 rows x 64 k (16 KiB)
  __shared__ __attribute__((aligned(16))) u16 Bsl[8192];  // 16 frags x 1 KiB (16 KiB)

  const int tid  = threadIdx.x;
  const int lane = tid & 63;
  const int wv   = tid >> 6;   // 0..3
  const int wr   = wv >> 1;    // row half (64 rows)
  const int wc   = wv & 1;     // col half (64 cols)

  const int bn = blockIdx.x & 7;   // == XCD under round-robin: B panel (1 MB) L2-pinned
  const int bm = blockIdx.x >> 3;
  const int m0 = bm * 128;
  const int n0 = bn * 128;

  const char* Hc = (const char*)H;
  const char* Wc = (const char*)Wt;

  // staging source offsets (4 x 16 B per thread each for A and B)
  size_t aSrc[4], bSrc[4];
#pragma unroll
  for (int p = 0; p < 4; ++p) {
    const int s = tid + 256 * p;
    const int row = s >> 3, ch = s & 7;
    // pre-swizzled source chunk: ch' = ch ^ (row&7); LDS dest stays linear (s*16)
    aSrc[p] = (size_t)(m0 + row) * (K_DIM * 2) + (size_t)(((u32)ch ^ ((u32)row & 7u)) * 16);
    const int f = s >> 6;  // 0..15: nf = f>>1, kk = f&1
    bSrc[p] = ((size_t)((bn * 8 + (f >> 1)) * 128 + (f & 1))) * 1024 + (size_t)(s & 63) * 16;
  }

  f32x4 acc[4][4];
#pragma unroll
  for (int i = 0; i < 4; ++i)
#pragma unroll
    for (int j = 0; j < 4; ++j)
      acc[i][j] = (f32x4){0.f, 0.f, 0.f, 0.f};

#pragma unroll 1
  for (int ks = 0; ks < 64; ++ks) {
    const size_t ka = (size_t)ks * 128;    // 64 k * 2 B per step
    const size_t kb = (size_t)ks * 2048;   // 2 kt-frags per step
#pragma unroll
    for (int p = 0; p < 4; ++p)
      async_cp16(Hc + aSrc[p] + ka, (char*)Asl + (size_t)(tid + 256 * p) * 16);
#pragma unroll
    for (int p = 0; p < 4; ++p)
      async_cp16(Wc + bSrc[p] + kb, (char*)Bsl + (size_t)(tid + 256 * p) * 16);
    __syncthreads();

    const char* ac = (const char*)Asl;
    const char* bc = (const char*)Bsl;
#pragma unroll
    for (int kk = 0; kk < 2; ++kk) {
      half8 ar[4], br[4];
#pragma unroll
      for (int i = 0; i < 4; ++i) {
        const int row = wr * 64 + i * 16 + (lane & 15);
        const u32 ch = ((u32)(kk * 4 + (lane >> 4))) ^ ((u32)lane & 7u);
        ar[i] = *(const half8*)(ac + (size_t)row * 128 + ch * 16);
      }
#pragma unroll
      for (int j = 0; j < 4; ++j)
        br[j] = *(const half8*)(bc + (size_t)(((wc * 4 + j) * 2 + kk) * 1024) + lane * 16);
#pragma unroll
      for (int i = 0; i < 4; ++i)
#pragma unroll
        for (int j = 0; j < 4; ++j)
          acc[i][j] = __builtin_amdgcn_mfma_f32_16x16x32_f16(ar[i], br[j], acc[i][j], 0, 0, 0);
    }
    __syncthreads();
  }

  // ---- epilogue: C/D layout col = lane&15, row = (lane>>4)*4 + reg [verified R0-R5] ----
  const int fr = lane & 15;
  const int rq = (lane >> 4) << 2;
  float bv[4];
#pragma unroll
  for (int j = 0; j < 4; ++j)
    bv[j] = Bias[n0 + wc * 64 + j * 16 + fr];
#pragma unroll
  for (int i = 0; i < 4; ++i) {
    const int row0 = m0 + wr * 64 + i * 16 + rq;
#pragma unroll
    for (int j = 0; j < 4; ++j) {
      const int col = n0 + wc * 64 + j * 16 + fr;
#pragma unroll
      for (int r = 0; r < 4; ++r)
        Out[(size_t)(row0 + r) * N_DIM + col] = acc[i][j][r] + bv[j];
    }
  }
}

// ---------------- fallback: verified R3 fused kernel (only if ws too small) ----------------
static constexpr int A_STRIDE = 40;

__global__ __launch_bounds__(256, 2)
void fused_fallback_kernel(const float* __restrict__ X, const float* __restrict__ W,
                           const float* __restrict__ Bias, const int* __restrict__ Mask,
                           float* __restrict__ Out) {
  __shared__ __attribute__((aligned(16))) _Float16 As[128 * A_STRIDE];
  __shared__ __attribute__((aligned(16))) _Float16 Bs[128 * 32];

  const int tid  = threadIdx.x;
  const int lane = tid & 63;
  const int wv   = tid >> 6;
  const int wr   = wv >> 1;
  const int wc   = wv & 1;
  const int bm = blockIdx.x & 63;
  const int bn = blockIdx.x >> 6;
  const int m0 = bm * 128;
  const int n0 = bn * 128;

  const int a_m = tid >> 1;
  const int a_k = (tid & 1) << 4;
  const float* xptr = X    + (size_t)(m0 + a_m) * K_DIM + a_k;
  const int*   mptr = Mask + (size_t)(m0 + a_m) * K_DIM + a_k;
  _Float16* a_lds = &As[a_m * A_STRIDE + a_k];

  const int i0 = tid, i1 = tid + 256;
  const float* wp0 = W + (size_t)(n0 + (i0 >> 2)) * K_DIM + ((i0 & 3) << 3);
  const float* wp1 = W + (size_t)(n0 + (i1 >> 2)) * K_DIM + ((i1 & 3) << 3);
  _Float16* bl0 = &Bs[i0 * 8];
  _Float16* bl1 = &Bs[i1 * 8];

  f32x4 acc[4][4];
#pragma unroll
  for (int i = 0; i < 4; ++i)
#pragma unroll
    for (int j = 0; j < 4; ++j)
      acc[i][j] = (f32x4){0.f, 0.f, 0.f, 0.f};

  float4 xf0 = *(const float4*)(xptr +  0);
  float4 xf1 = *(const float4*)(xptr +  4);
  float4 xf2 = *(const float4*)(xptr +  8);
  float4 xf3 = *(const float4*)(xptr + 12);
  uint4  mr0 = *(const uint4*)(mptr +  0);
  uint4  mr1 = *(const uint4*)(mptr +  4);
  uint4  mr2 = *(const uint4*)(mptr +  8);
  uint4  mr3 = *(const uint4*)(mptr + 12);
  float4 wf0 = *(const float4*)(wp0 + 0);
  float4 wf1 = *(const float4*)(wp0 + 4);
  float4 wf2 = *(const float4*)(wp1 + 0);
  float4 wf3 = *(const float4*)(wp1 + 4);

#pragma unroll 1
  for (int kt = 0; kt < 128; ++kt) {
    {
      float xs[16] = {xf0.x, xf0.y, xf0.z, xf0.w, xf1.x, xf1.y, xf1.z, xf1.w,
                      xf2.x, xf2.y, xf2.z, xf2.w, xf3.x, xf3.y, xf3.z, xf3.w};
      u32 mk[16]   = {mr0.x, mr0.y, mr0.z, mr0.w, mr1.x, mr1.y, mr1.z, mr1.w,
                      mr2.x, mr2.y, mr2.z, mr2.w, mr3.x, mr3.y, mr3.z, mr3.w};
      u32 ow[8];
#pragma unroll
      for (int e = 0; e < 8; ++e)
        ow[e] = pack2(gelu_drop(xs[2 * e], mk[2 * e]), gelu_drop(xs[2 * e + 1], mk[2 * e + 1]));
      ((uint4*)a_lds)[0] = make_uint4(ow[0], ow[1], ow[2], ow[3]);
      ((uint4*)a_lds)[1] = make_uint4(ow[4], ow[5], ow[6], ow[7]);
    }
    {
      *(uint4*)bl0 = make_uint4(pack2(wf0.x, wf0.y), pack2(wf0.z, wf0.w),
                                pack2(wf1.x, wf1.y), pack2(wf1.z, wf1.w));
      *(uint4*)bl1 = make_uint4(pack2(wf2.x, wf2.y), pack2(wf2.z, wf2.w),
                                pack2(wf3.x, wf3.y), pack2(wf3.z, wf3.w));
    }
    __syncthreads();

    if (kt + 1 < 128) {
      xptr += 32; mptr += 32; wp0 += 32; wp1 += 32;
      xf0 = *(const float4*)(xptr +  0);
      xf1 = *(const float4*)(xptr +  4);
      xf2 = *(const float4*)(xptr +  8);
      xf3 = *(const float4*)(xptr + 12);
      mr0 = *(const uint4*)(mptr +  0);
      mr1 = *(const uint4*)(mptr +  4);
      mr2 = *(const uint4*)(mptr +  8);
      mr3 = *(const uint4*)(mptr + 12);
      wf0 = *(const float4*)(wp0 + 0);
      wf1 = *(const float4*)(wp0 + 4);
      wf2 = *(const float4*)(wp1 + 0);
      wf3 = *(const float4*)(wp1 + 4);
    }

    {
      const int fr2 = lane & 15;
      const int fk2 = (lane >> 4) << 3;
      half8 ar[4], br[4];
#pragma unroll
      for (int i = 0; i < 4; ++i)
        ar[i] = *(const half8*)&As[(wr * 64 + i * 16 + fr2) * A_STRIDE + fk2];
#pragma unroll
      for (int j = 0; j < 4; ++j)
        br[j] = *(const half8*)&Bs[(wc * 64 + j * 16 + fr2) * 32 + fk2];
#pragma unroll
      for (int i = 0; i < 4; ++i)
#pragma unroll
        for (int j = 0; j < 4; ++j)
          acc[i][j] = __builtin_amdgcn_mfma_f32_16x16x32_f16(ar[i], br[j], acc[i][j], 0, 0, 0);
    }
    __syncthreads();
  }

  const int fr = lane & 15;
  const int rq = (lane >> 4) << 2;
  float bv[4];
#pragma unroll
  for (int j = 0; j < 4; ++j)
    bv[j] = Bias[n0 + wc * 64 + j * 16 + fr];
#pragma unroll
  for (int i = 0; i < 4; ++i) {
    const int row0 = m0 + wr * 64 + i * 16 + rq;
#pragma unroll
    for (int j = 0; j < 4; ++j) {
      const int col = n0 + wc * 64 + j * 16 + fr;
#pragma unroll
      for (int r = 0; r < 4; ++r)
        Out[(size_t)(row0 + r) * N_DIM + col] = acc[i][j][r] + bv[j];
    }
  }
}

extern "C" void kernel_launch(void* const* d_in, const int* in_sizes, int n_in,
                              void* d_out, int out_size, void* d_ws, size_t ws_size,
                              hipStream_t stream) {
  const float* X    = (const float*)d_in[0];   // x (8192x4096), fp16 canonicalized to f32
  const float* W    = (const float*)d_in[1];   // weight (1024x4096) f32, K-contiguous
  const float* Bias = (const float*)d_in[2];   // bias (1024) f32
  const int*   Mk   = (const int*)d_in[3];     // keep-mask int32 0/1
  float* Out = (float*)d_out;                  // y (8192x1024) f32

  if (ws_size >= WS_NEEDED) {
    u16* H  = (u16*)d_ws;
    u16* Wt = (u16*)((char*)d_ws + H_BYTES);
    pack_kernel<<<WPACK_BLOCKS + PACKX_BLOCKS, 256, 0, stream>>>(X, Mk, W, H, Wt);
    gemm_kernel<<<(M_DIM / 128) * (N_DIM / 128), 256, 0, stream>>>(H, Wt, Bias, Out);  // 512 blocks
  } else {
    fused_fallback_kernel<<<64 * 8, 256, 0, stream>>>(X, W, Bias, Mk, Out);
  }
}

// Round 8
// 390.999 us; speedup vs baseline: 1.0648x; 1.0648x over previous
//
#include <hip/hip_runtime.h>
#include <stdint.h>

typedef uint32_t u32;
typedef uint16_t u16;

static constexpr int M_DIM = 8192;
static constexpr int N_DIM = 1024;
static constexpr int K_DIM = 4096;

// ws layout: H row-major fp16 [8192][4096] (64 MiB) + Wt frag-major (8 MiB)
static constexpr size_t H_BYTES  = (size_t)M_DIM * K_DIM * 2;   // 64 MiB
static constexpr size_t FRAG_U16 = 512;
static constexpr size_t WT_BYTES = 64ull * 128 * FRAG_U16 * 2;  // 8 MiB
static constexpr size_t WS_NEEDED = H_BYTES + WT_BYTES;         // 72 MiB

typedef __attribute__((ext_vector_type(8))) _Float16 half8;  // MFMA A/B frag (4 VGPRs)
typedef __attribute__((ext_vector_type(4))) float f32x4;     // MFMA C/D frag

__device__ __forceinline__ u32 pack2(float a, float b) {
  union { _Float16 h[2]; u32 u; } p;
  p.h[0] = (_Float16)a;   // v_cvt_f16_f32, RNE
  p.h[1] = (_Float16)b;
  return p.u;
}

// GELU via Abramowitz-Stegun 7.1.26 erf (|err| <= 1.5e-7) + dropout keep-mask * 1/(1-0.1).
__device__ __forceinline__ float gelu_drop(float x, u32 keep) {
  float ax = fabsf(x);
  float z  = ax * 0.70710678f;
  float t  = __builtin_amdgcn_rcpf(fmaf(0.3275911f, z, 1.0f));
  float poly = fmaf(fmaf(fmaf(fmaf(1.061405429f, t, -1.453152027f),
                              t, 1.421413741f),
                         t, -0.284496736f),
                    t, 0.254829592f) * t;
  float e   = exp2f(z * z * -1.44269504f);    // exp(-z^2)
  float erf = fmaf(-poly, e, 1.0f);           // erf(|x|/sqrt(2)) in [0,1)
  float g   = 0.5f * x * (1.0f + copysignf(erf, x));
  return keep ? g * 1.1111112f : 0.0f;
}

__device__ __forceinline__ void async_cp16(const void* g, void* l) {
  __builtin_amdgcn_global_load_lds((__attribute__((address_space(1))) u32*)g,
                                   (__attribute__((address_space(3))) u32*)l,
                                   16, 0, 0);
}

// ---------------- pass 1 (merged): W prepack + X gelu-pack to ROW-MAJOR H ----------------
// blocks [0, WPACK_BLOCKS): verified W prepack (17 MB f32 -> 8 MB fp16 frag-major).
// blocks [WPACK_BLOCKS, +PACKX_BLOCKS): LANE-INTERLEAVED grid-stride gelu pack:
//   thread handles ONE float4 granule per sweep at i = gtid + sweep*STRIDE, so every
//   load instruction is 1 KB dense per wave (lane i at byte lane*16) and every store
//   is 512 B dense. 16 sweeps, 2-deep register pipeline.
static constexpr int W_PAIRS = 64 * 64;
static constexpr int WPACK_BLOCKS = W_PAIRS / 4;    // 1024
static constexpr int PACKX_BLOCKS = 2048;
static constexpr u32 PACK_THREADS = PACKX_BLOCKS * 256;             // 524288
static constexpr u32 PACK_GRANULES = (u32)((size_t)M_DIM * K_DIM / 4);  // 8388608
static constexpr int PACK_SWEEPS = PACK_GRANULES / PACK_THREADS;    // 16

__global__ __launch_bounds__(256)
void pack_kernel(const float* __restrict__ X, const int* __restrict__ Mask,
                 const float* __restrict__ W, u16* __restrict__ H, u16* __restrict__ Wt) {
  if (blockIdx.x < WPACK_BLOCKS) {
    // ---- W prepack (verified R3-R7, unchanged) ----
    const int l     = threadIdx.x & 63;
    const int pj    = blockIdx.x * 4 + (threadIdx.x >> 6);
    const int row16 = l & 15;
    const int kof   = (l >> 4) << 4;
    const int fsub  = kof >> 5;
    const int q0    = (kof & 31) >> 3;
    const int nb = pj >> 6, kp = pj & 63;
    const float* wp = W + (size_t)(nb * 16 + row16) * K_DIM + kp * 64 + kof;
    float4 w0 = *(const float4*)(wp + 0);
    float4 w1 = *(const float4*)(wp + 4);
    float4 w2 = *(const float4*)(wp + 8);
    float4 w3 = *(const float4*)(wp + 12);
    const int f = kp * 2 + fsub;
    u16* dst = Wt + (size_t)(nb * 128 + f) * FRAG_U16 + (size_t)(row16 + 16 * q0) * 8;
    *(uint4*)(dst)       = make_uint4(pack2(w0.x, w0.y), pack2(w0.z, w0.w),
                                      pack2(w1.x, w1.y), pack2(w1.z, w1.w));
    *(uint4*)(dst + 128) = make_uint4(pack2(w2.x, w2.y), pack2(w2.z, w2.w),
                                      pack2(w3.x, w3.y), pack2(w3.z, w3.w));
    return;
  }

  const u32 t0 = (blockIdx.x - WPACK_BLOCKS) * 256 + threadIdx.x;  // 0..524287
  const float4* Xv = (const float4*)X;
  const uint4*  Mv = (const uint4*)Mask;

  u32 i = t0;
  float4 xA = Xv[i];
  uint4  mA = Mv[i];
  float4 xB;
  uint4  mB;

#pragma unroll
  for (int it = 0; it < PACK_SWEEPS; ++it) {
    const u32 inext = i + PACK_THREADS;
    if (it + 1 < PACK_SWEEPS) {
      xB = Xv[inext];
      mB = Mv[inext];
    }
    const u32 lo = pack2(gelu_drop(xA.x, mA.x), gelu_drop(xA.y, mA.y));
    const u32 hi = pack2(gelu_drop(xA.z, mA.z), gelu_drop(xA.w, mA.w));
    *(uint2*)(H + (size_t)i * 4) = make_uint2(lo, hi);   // 8 B dense store
    i = inext;
    xA = xB;
    mA = mB;
  }
}

// ---------------- pass 2: 128x128 GEMM, double-buffered, XCD-co-located H stripes ----------------
// 512 blocks x 256 threads (4 waves, 2x2 of 64x64), 2 blocks/CU (LDS 64 KB each).
// XCD mapping (round-robin dispatch: XCD = bid & 7): XCD x owns bm in [8x, 8x+8) x all bn.
//   All 8 readers of each H stripe are co-resident on ONE XCD -> H served from its L2;
//   HBM fetch ~ H 64 MB + Wt 8 MB (once).
// A staged via global_load_lds with PRE-SWIZZLED source (verified R7): LDS dest linear,
// effective layout [row][k ^ ((row&7) slot)]; ds_read applies the same XOR -> conflict-free.
// B staged linear from frag-major Wt (verified R0/R7 path).
__global__ __launch_bounds__(256, 2)
void gemm_kernel(const u16* __restrict__ H, const u16* __restrict__ Wt,
                 const float* __restrict__ Bias, float* __restrict__ Out) {
  __shared__ __attribute__((aligned(16))) u16 Asl[2][8192];  // 2 x 16 KiB
  __shared__ __attribute__((aligned(16))) u16 Bsl[2][8192];  // 2 x 16 KiB

  const int tid  = threadIdx.x;
  const int lane = tid & 63;
  const int wv   = tid >> 6;   // 0..3
  const int wr   = wv >> 1;    // row half (64 rows)
  const int wc   = wv & 1;     // col half (64 cols)

  const int x  = blockIdx.x & 7;        // XCD under round-robin dispatch
  const int j  = blockIdx.x >> 3;       // 0..63
  const int bm = x * 8 + (j & 7);       // 0..63 : XCD x owns 8 contiguous stripes
  const int bn = j >> 3;                // 0..7
  const int m0 = bm * 128;
  const int n0 = bn * 128;

  const char* Hc = (const char*)H;
  const char* Wc = (const char*)Wt;

  // staging source offsets (4 x 16 B per thread each for A and B) [verified R7]
  size_t aSrc[4], bSrc[4];
#pragma unroll
  for (int p = 0; p < 4; ++p) {
    const int s = tid + 256 * p;
    const int row = s >> 3, ch = s & 7;
    // pre-swizzled source chunk: ch' = ch ^ (row&7); LDS dest stays linear (s*16)
    aSrc[p] = (size_t)(m0 + row) * (K_DIM * 2) + (size_t)(((u32)ch ^ ((u32)row & 7u)) * 16);
    const int f = s >> 6;  // 0..15: nf = f>>1, kk = f&1
    bSrc[p] = ((size_t)((bn * 8 + (f >> 1)) * 128 + (f & 1))) * 1024 + (size_t)(s & 63) * 16;
  }

  auto stage = [&](int ks, int buf) {
    const size_t ka = (size_t)ks * 128;    // 64 k * 2 B per step
    const size_t kb = (size_t)ks * 2048;   // 2 kt-frags per step
#pragma unroll
    for (int p = 0; p < 4; ++p)
      async_cp16(Hc + aSrc[p] + ka, (char*)Asl[buf] + (size_t)(tid + 256 * p) * 16);
#pragma unroll
    for (int p = 0; p < 4; ++p)
      async_cp16(Wc + bSrc[p] + kb, (char*)Bsl[buf] + (size_t)(tid + 256 * p) * 16);
  };

  f32x4 acc[4][4];
#pragma unroll
  for (int i = 0; i < 4; ++i)
#pragma unroll
    for (int jj = 0; jj < 4; ++jj)
      acc[i][jj] = (f32x4){0.f, 0.f, 0.f, 0.f};

  // prologue: stage ks=0 into buf 0
  stage(0, 0);
  __syncthreads();

  int buf = 0;
#pragma unroll 1
  for (int ks = 0; ks < 64; ++ks) {
    if (ks + 1 < 64) stage(ks + 1, buf ^ 1);   // prefetch while computing

    const char* ac = (const char*)Asl[buf];
    const char* bc = (const char*)Bsl[buf];
#pragma unroll
    for (int kk = 0; kk < 2; ++kk) {
      half8 ar[4], br[4];
#pragma unroll
      for (int i = 0; i < 4; ++i) {
        const int row = wr * 64 + i * 16 + (lane & 15);
        const u32 ch = ((u32)(kk * 4 + (lane >> 4))) ^ ((u32)lane & 7u);
        ar[i] = *(const half8*)(ac + (size_t)row * 128 + ch * 16);
      }
#pragma unroll
      for (int jj = 0; jj < 4; ++jj)
        br[jj] = *(const half8*)(bc + (size_t)(((wc * 4 + jj) * 2 + kk) * 1024) + lane * 16);
#pragma unroll
      for (int i = 0; i < 4; ++i)
#pragma unroll
        for (int jj = 0; jj < 4; ++jj)
          acc[i][jj] = __builtin_amdgcn_mfma_f32_16x16x32_f16(ar[i], br[jj], acc[i][jj], 0, 0, 0);
    }
    __syncthreads();   // staging of ks+1 drained (compiler vmcnt) + all reads of buf done
    buf ^= 1;
  }

  // ---- epilogue: C/D layout col = lane&15, row = (lane>>4)*4 + reg [verified R0-R7] ----
  const int fr = lane & 15;
  const int rq = (lane >> 4) << 2;
  float bv[4];
#pragma unroll
  for (int jj = 0; jj < 4; ++jj)
    bv[jj] = Bias[n0 + wc * 64 + jj * 16 + fr];
#pragma unroll
  for (int i = 0; i < 4; ++i) {
    const int row0 = m0 + wr * 64 + i * 16 + rq;
#pragma unroll
    for (int jj = 0; jj < 4; ++jj) {
      const int col = n0 + wc * 64 + jj * 16 + fr;
#pragma unroll
      for (int r = 0; r < 4; ++r)
        Out[(size_t)(row0 + r) * N_DIM + col] = acc[i][jj][r] + bv[jj];
    }
  }
}

// ---------------- fallback: verified R3 fused kernel (only if ws too small) ----------------
static constexpr int A_STRIDE = 40;

__global__ __launch_bounds__(256, 2)
void fused_fallback_kernel(const float* __restrict__ X, const float* __restrict__ W,
                           const float* __restrict__ Bias, const int* __restrict__ Mask,
                           float* __restrict__ Out) {
  __shared__ __attribute__((aligned(16))) _Float16 As[128 * A_STRIDE];
  __shared__ __attribute__((aligned(16))) _Float16 Bs[128 * 32];

  const int tid  = threadIdx.x;
  const int lane = tid & 63;
  const int wv   = tid >> 6;
  const int wr   = wv >> 1;
  const int wc   = wv & 1;
  const int bm = blockIdx.x & 63;
  const int bn = blockIdx.x >> 6;
  const int m0 = bm * 128;
  const int n0 = bn * 128;

  const int a_m = tid >> 1;
  const int a_k = (tid & 1) << 4;
  const float* xptr = X    + (size_t)(m0 + a_m) * K_DIM + a_k;
  const int*   mptr = Mask + (size_t)(m0 + a_m) * K_DIM + a_k;
  _Float16* a_lds = &As[a_m * A_STRIDE + a_k];

  const int i0 = tid, i1 = tid + 256;
  const float* wp0 = W + (size_t)(n0 + (i0 >> 2)) * K_DIM + ((i0 & 3) << 3);
  const float* wp1 = W + (size_t)(n0 + (i1 >> 2)) * K_DIM + ((i1 & 3) << 3);
  _Float16* bl0 = &Bs[i0 * 8];
  _Float16* bl1 = &Bs[i1 * 8];

  f32x4 acc[4][4];
#pragma unroll
  for (int i = 0; i < 4; ++i)
#pragma unroll
    for (int j = 0; j < 4; ++j)
      acc[i][j] = (f32x4){0.f, 0.f, 0.f, 0.f};

  float4 xf0 = *(const float4*)(xptr +  0);
  float4 xf1 = *(const float4*)(xptr +  4);
  float4 xf2 = *(const float4*)(xptr +  8);
  float4 xf3 = *(const float4*)(xptr + 12);
  uint4  mr0 = *(const uint4*)(mptr +  0);
  uint4  mr1 = *(const uint4*)(mptr +  4);
  uint4  mr2 = *(const uint4*)(mptr +  8);
  uint4  mr3 = *(const uint4*)(mptr + 12);
  float4 wf0 = *(const float4*)(wp0 + 0);
  float4 wf1 = *(const float4*)(wp0 + 4);
  float4 wf2 = *(const float4*)(wp1 + 0);
  float4 wf3 = *(const float4*)(wp1 + 4);

#pragma unroll 1
  for (int kt = 0; kt < 128; ++kt) {
    {
      float xs[16] = {xf0.x, xf0.y, xf0.z, xf0.w, xf1.x, xf1.y, xf1.z, xf1.w,
                      xf2.x, xf2.y, xf2.z, xf2.w, xf3.x, xf3.y, xf3.z, xf3.w};
      u32 mk[16]   = {mr0.x, mr0.y, mr0.z, mr0.w, mr1.x, mr1.y, mr1.z, mr1.w,
                      mr2.x, mr2.y, mr2.z, mr2.w, mr3.x, mr3.y, mr3.z, mr3.w};
      u32 ow[8];
#pragma unroll
      for (int e = 0; e < 8; ++e)
        ow[e] = pack2(gelu_drop(xs[2 * e], mk[2 * e]), gelu_drop(xs[2 * e + 1], mk[2 * e + 1]));
      ((uint4*)a_lds)[0] = make_uint4(ow[0], ow[1], ow[2], ow[3]);
      ((uint4*)a_lds)[1] = make_uint4(ow[4], ow[5], ow[6], ow[7]);
    }
    {
      *(uint4*)bl0 = make_uint4(pack2(wf0.x, wf0.y), pack2(wf0.z, wf0.w),
                                pack2(wf1.x, wf1.y), pack2(wf1.z, wf1.w));
      *(uint4*)bl1 = make_uint4(pack2(wf2.x, wf2.y), pack2(wf2.z, wf2.w),
                                pack2(wf3.x, wf3.y), pack2(wf3.z, wf3.w));
    }
    __syncthreads();

    if (kt + 1 < 128) {
      xptr += 32; mptr += 32; wp0 += 32; wp1 += 32;
      xf0 = *(const float4*)(xptr +  0);
      xf1 = *(const float4*)(xptr +  4);
      xf2 = *(const float4*)(xptr +  8);
      xf3 = *(const float4*)(xptr + 12);
      mr0 = *(const uint4*)(mptr +  0);
      mr1 = *(const uint4*)(mptr +  4);
      mr2 = *(const uint4*)(mptr +  8);
      mr3 = *(const uint4*)(mptr + 12);
      wf0 = *(const float4*)(wp0 + 0);
      wf1 = *(const float4*)(wp0 + 4);
      wf2 = *(const float4*)(wp1 + 0);
      wf3 = *(const float4*)(wp1 + 4);
    }

    {
      const int fr2 = lane & 15;
      const int fk2 = (lane >> 4) << 3;
      half8 ar[4], br[4];
#pragma unroll
      for (int i = 0; i < 4; ++i)
        ar[i] = *(const half8*)&As[(wr * 64 + i * 16 + fr2) * A_STRIDE + fk2];
#pragma unroll
      for (int j = 0; j < 4; ++j)
        br[j] = *(const half8*)&Bs[(wc * 64 + j * 16 + fr2) * 32 + fk2];
#pragma unroll
      for (int i = 0; i < 4; ++i)
#pragma unroll
        for (int j = 0; j < 4; ++j)
          acc[i][j] = __builtin_amdgcn_mfma_f32_16x16x32_f16(ar[i], br[j], acc[i][j], 0, 0, 0);
    }
    __syncthreads();
  }

  const int fr = lane & 15;
  const int rq = (lane >> 4) << 2;
  float bv[4];
#pragma unroll
  for (int j = 0; j < 4; ++j)
    bv[j] = Bias[n0 + wc * 64 + j * 16 + fr];
#pragma unroll
  for (int i = 0; i < 4; ++i) {
    const int row0 = m0 + wr * 64 + i * 16 + rq;
#pragma unroll
    for (int j = 0; j < 4; ++j) {
      const int col = n0 + wc * 64 + j * 16 + fr;
#pragma unroll
      for (int r = 0; r < 4; ++r)
        Out[(size_t)(row0 + r) * N_DIM + col] = acc[i][j][r] + bv[j];
    }
  }
}

extern "C" void kernel_launch(void* const* d_in, const int* in_sizes, int n_in,
                              void* d_out, int out_size, void* d_ws, size_t ws_size,
                              hipStream_t stream) {
  const float* X    = (const float*)d_in[0];   // x (8192x4096), fp16 canonicalized to f32
  const float* W    = (const float*)d_in[1];   // weight (1024x4096) f32, K-contiguous
  const float* Bias = (const float*)d_in[2];   // bias (1024) f32
  const int*   Mk   = (const int*)d_in[3];     // keep-mask int32 0/1
  float* Out = (float*)d_out;                  // y (8192x1024) f32

  if (ws_size >= WS_NEEDED) {
    u16* H  = (u16*)d_ws;
    u16* Wt = (u16*)((char*)d_ws + H_BYTES);
    pack_kernel<<<WPACK_BLOCKS + PACKX_BLOCKS, 256, 0, stream>>>(X, Mk, W, H, Wt);
    gemm_kernel<<<(M_DIM / 128) * (N_DIM / 128), 256, 0, stream>>>(H, Wt, Bias, Out);  // 512 blocks
  } else {
    fused_fallback_kernel<<<64 * 8, 256, 0, stream>>>(X, W, Bias, Mk, Out);
  }
}

// Round 9
// 388.511 us; speedup vs baseline: 1.0717x; 1.0064x over previous
//
#include <hip/hip_runtime.h>
#include <stdint.h>

typedef uint32_t u32;
typedef uint16_t u16;

static constexpr int M_DIM = 8192;
static constexpr int N_DIM = 1024;
static constexpr int K_DIM = 4096;

// ws layout: H row-major fp16 [8192][4096] (64 MiB) + Wt frag-major (8 MiB)
static constexpr size_t H_BYTES  = (size_t)M_DIM * K_DIM * 2;   // 64 MiB
static constexpr size_t FRAG_U16 = 512;
static constexpr size_t WT_BYTES = 64ull * 128 * FRAG_U16 * 2;  // 8 MiB
static constexpr size_t WS_NEEDED = H_BYTES + WT_BYTES;         // 72 MiB

typedef __attribute__((ext_vector_type(8))) _Float16 half8;  // MFMA A/B frag (4 VGPRs)
typedef __attribute__((ext_vector_type(4))) float f32x4;     // MFMA C/D frag

__device__ __forceinline__ u32 pack2(float a, float b) {
  union { _Float16 h[2]; u32 u; } p;
  p.h[0] = (_Float16)a;   // v_cvt_f16_f32, RNE
  p.h[1] = (_Float16)b;
  return p.u;
}

// GELU via Abramowitz-Stegun 7.1.26 erf (|err| <= 1.5e-7) + dropout keep-mask * 1/(1-0.1).
__device__ __forceinline__ float gelu_drop(float x, u32 keep) {
  float ax = fabsf(x);
  float z  = ax * 0.70710678f;
  float t  = __builtin_amdgcn_rcpf(fmaf(0.3275911f, z, 1.0f));
  float poly = fmaf(fmaf(fmaf(fmaf(1.061405429f, t, -1.453152027f),
                              t, 1.421413741f),
                         t, -0.284496736f),
                    t, 0.254829592f) * t;
  float e   = exp2f(z * z * -1.44269504f);    // exp(-z^2)
  float erf = fmaf(-poly, e, 1.0f);           // erf(|x|/sqrt(2)) in [0,1)
  float g   = 0.5f * x * (1.0f + copysignf(erf, x));
  return keep ? g * 1.1111112f : 0.0f;
}

__device__ __forceinline__ void async_cp16(const void* g, void* l) {
  __builtin_amdgcn_global_load_lds((__attribute__((address_space(1))) u32*)g,
                                   (__attribute__((address_space(3))) u32*)l,
                                   16, 0, 0);
}

// ---------------- pass 1 (merged): W prepack + X gelu-pack to ROW-MAJOR H ----------------
// blocks [0, WPACK_BLOCKS): verified W prepack (17 MB f32 -> 8 MB fp16 frag-major).
// blocks [WPACK_BLOCKS, +PACKX_BLOCKS): PERSISTENT exact-fill streaming gelu pack:
//   2048 total blocks = 8192 waves = exactly one 32-wave/CU round (no ragged tail).
//   Each thread: 32 lane-interleaved granules, 4-deep register pipeline (8 loads /
//   128 B per lane continuously outstanding). Loads/stores dense per instruction.
static constexpr int W_PAIRS = 64 * 64;
static constexpr int WPACK_BLOCKS = W_PAIRS / 4;    // 1024
static constexpr int PACKX_BLOCKS = 1024;
static constexpr u32 PACK_THREADS = PACKX_BLOCKS * 256;             // 262144
static constexpr u32 PACK_GRANULES = (u32)((size_t)M_DIM * K_DIM / 4);  // 8388608
static constexpr int PACK_SWEEPS = PACK_GRANULES / PACK_THREADS;    // 32

__global__ __launch_bounds__(256)
void pack_kernel(const float* __restrict__ X, const int* __restrict__ Mask,
                 const float* __restrict__ W, u16* __restrict__ H, u16* __restrict__ Wt) {
  if (blockIdx.x < WPACK_BLOCKS) {
    // ---- W prepack (verified R3-R8, unchanged) ----
    const int l     = threadIdx.x & 63;
    const int pj    = blockIdx.x * 4 + (threadIdx.x >> 6);
    const int row16 = l & 15;
    const int kof   = (l >> 4) << 4;
    const int fsub  = kof >> 5;
    const int q0    = (kof & 31) >> 3;
    const int nb = pj >> 6, kp = pj & 63;
    const float* wp = W + (size_t)(nb * 16 + row16) * K_DIM + kp * 64 + kof;
    float4 w0 = *(const float4*)(wp + 0);
    float4 w1 = *(const float4*)(wp + 4);
    float4 w2 = *(const float4*)(wp + 8);
    float4 w3 = *(const float4*)(wp + 12);
    const int f = kp * 2 + fsub;
    u16* dst = Wt + (size_t)(nb * 128 + f) * FRAG_U16 + (size_t)(row16 + 16 * q0) * 8;
    *(uint4*)(dst)       = make_uint4(pack2(w0.x, w0.y), pack2(w0.z, w0.w),
                                      pack2(w1.x, w1.y), pack2(w1.z, w1.w));
    *(uint4*)(dst + 128) = make_uint4(pack2(w2.x, w2.y), pack2(w2.z, w2.w),
                                      pack2(w3.x, w3.y), pack2(w3.z, w3.w));
    return;
  }

  const u32 t0 = (blockIdx.x - WPACK_BLOCKS) * 256 + threadIdx.x;  // 0..262143
  const float4* Xv = (const float4*)X;
  const uint4*  Mv = (const uint4*)Mask;

  float4 xs[4];
  uint4  ms[4];

  // prologue: fill the 4-deep pipeline (8 loads in flight)
#pragma unroll
  for (int s = 0; s < 4; ++s) {
    const u32 g = t0 + (u32)s * PACK_THREADS;
    xs[s] = Xv[g];
    ms[s] = Mv[g];
  }

#pragma unroll
  for (int s = 0; s < PACK_SWEEPS; ++s) {
    const int slot = s & 3;
    const u32 g = t0 + (u32)s * PACK_THREADS;
    const u32 lo = pack2(gelu_drop(xs[slot].x, ms[slot].x), gelu_drop(xs[slot].y, ms[slot].y));
    const u32 hi = pack2(gelu_drop(xs[slot].z, ms[slot].z), gelu_drop(xs[slot].w, ms[slot].w));
    *(uint2*)(H + (size_t)g * 4) = make_uint2(lo, hi);   // 8 B dense store
    if (s + 4 < PACK_SWEEPS) {
      const u32 gn = t0 + (u32)(s + 4) * PACK_THREADS;
      xs[slot] = Xv[gn];
      ms[slot] = Mv[gn];
    }
  }
}

// ---------------- pass 2: 128x128 GEMM, double-buffered, XCD-co-located H stripes ----------------
// (verified R8: ~99 us — UNCHANGED this round)
// 512 blocks x 256 threads (4 waves, 2x2 of 64x64), 2 blocks/CU (LDS 64 KB each).
// XCD mapping (round-robin dispatch: XCD = bid & 7): XCD x owns bm in [8x, 8x+8) x all bn.
// A staged via global_load_lds with PRE-SWIZZLED source: LDS dest linear, effective
// layout [row][k ^ ((row&7) slot)]; ds_read applies the same XOR -> conflict-free.
// B staged linear from frag-major Wt.
__global__ __launch_bounds__(256, 2)
void gemm_kernel(const u16* __restrict__ H, const u16* __restrict__ Wt,
                 const float* __restrict__ Bias, float* __restrict__ Out) {
  __shared__ __attribute__((aligned(16))) u16 Asl[2][8192];  // 2 x 16 KiB
  __shared__ __attribute__((aligned(16))) u16 Bsl[2][8192];  // 2 x 16 KiB

  const int tid  = threadIdx.x;
  const int lane = tid & 63;
  const int wv   = tid >> 6;   // 0..3
  const int wr   = wv >> 1;    // row half (64 rows)
  const int wc   = wv & 1;     // col half (64 cols)

  const int x  = blockIdx.x & 7;        // XCD under round-robin dispatch
  const int j  = blockIdx.x >> 3;       // 0..63
  const int bm = x * 8 + (j & 7);       // 0..63 : XCD x owns 8 contiguous stripes
  const int bn = j >> 3;                // 0..7
  const int m0 = bm * 128;
  const int n0 = bn * 128;

  const char* Hc = (const char*)H;
  const char* Wc = (const char*)Wt;

  // staging source offsets (4 x 16 B per thread each for A and B) [verified R7/R8]
  size_t aSrc[4], bSrc[4];
#pragma unroll
  for (int p = 0; p < 4; ++p) {
    const int s = tid + 256 * p;
    const int row = s >> 3, ch = s & 7;
    // pre-swizzled source chunk: ch' = ch ^ (row&7); LDS dest stays linear (s*16)
    aSrc[p] = (size_t)(m0 + row) * (K_DIM * 2) + (size_t)(((u32)ch ^ ((u32)row & 7u)) * 16);
    const int f = s >> 6;  // 0..15: nf = f>>1, kk = f&1
    bSrc[p] = ((size_t)((bn * 8 + (f >> 1)) * 128 + (f & 1))) * 1024 + (size_t)(s & 63) * 16;
  }

  auto stage = [&](int ks, int buf) {
    const size_t ka = (size_t)ks * 128;    // 64 k * 2 B per step
    const size_t kb = (size_t)ks * 2048;   // 2 kt-frags per step
#pragma unroll
    for (int p = 0; p < 4; ++p)
      async_cp16(Hc + aSrc[p] + ka, (char*)Asl[buf] + (size_t)(tid + 256 * p) * 16);
#pragma unroll
    for (int p = 0; p < 4; ++p)
      async_cp16(Wc + bSrc[p] + kb, (char*)Bsl[buf] + (size_t)(tid + 256 * p) * 16);
  };

  f32x4 acc[4][4];
#pragma unroll
  for (int i = 0; i < 4; ++i)
#pragma unroll
    for (int jj = 0; jj < 4; ++jj)
      acc[i][jj] = (f32x4){0.f, 0.f, 0.f, 0.f};

  // prologue: stage ks=0 into buf 0
  stage(0, 0);
  __syncthreads();

  int buf = 0;
#pragma unroll 1
  for (int ks = 0; ks < 64; ++ks) {
    if (ks + 1 < 64) stage(ks + 1, buf ^ 1);   // prefetch while computing

    const char* ac = (const char*)Asl[buf];
    const char* bc = (const char*)Bsl[buf];
#pragma unroll
    for (int kk = 0; kk < 2; ++kk) {
      half8 ar[4], br[4];
#pragma unroll
      for (int i = 0; i < 4; ++i) {
        const int row = wr * 64 + i * 16 + (lane & 15);
        const u32 ch = ((u32)(kk * 4 + (lane >> 4))) ^ ((u32)lane & 7u);
        ar[i] = *(const half8*)(ac + (size_t)row * 128 + ch * 16);
      }
#pragma unroll
      for (int jj = 0; jj < 4; ++jj)
        br[jj] = *(const half8*)(bc + (size_t)(((wc * 4 + jj) * 2 + kk) * 1024) + lane * 16);
#pragma unroll
      for (int i = 0; i < 4; ++i)
#pragma unroll
        for (int jj = 0; jj < 4; ++jj)
          acc[i][jj] = __builtin_amdgcn_mfma_f32_16x16x32_f16(ar[i], br[jj], acc[i][jj], 0, 0, 0);
    }
    __syncthreads();   // staging of ks+1 drained (compiler vmcnt) + all reads of buf done
    buf ^= 1;
  }

  // ---- epilogue: C/D layout col = lane&15, row = (lane>>4)*4 + reg [verified R0-R8] ----
  const int fr = lane & 15;
  const int rq = (lane >> 4) << 2;
  float bv[4];
#pragma unroll
  for (int jj = 0; jj < 4; ++jj)
    bv[jj] = Bias[n0 + wc * 64 + jj * 16 + fr];
#pragma unroll
  for (int i = 0; i < 4; ++i) {
    const int row0 = m0 + wr * 64 + i * 16 + rq;
#pragma unroll
    for (int jj = 0; jj < 4; ++jj) {
      const int col = n0 + wc * 64 + jj * 16 + fr;
#pragma unroll
      for (int r = 0; r < 4; ++r)
        Out[(size_t)(row0 + r) * N_DIM + col] = acc[i][jj][r] + bv[jj];
    }
  }
}

// ---------------- fallback: verified R3 fused kernel (only if ws too small) ----------------
static constexpr int A_STRIDE = 40;

__global__ __launch_bounds__(256, 2)
void fused_fallback_kernel(const float* __restrict__ X, const float* __restrict__ W,
                           const float* __restrict__ Bias, const int* __restrict__ Mask,
                           float* __restrict__ Out) {
  __shared__ __attribute__((aligned(16))) _Float16 As[128 * A_STRIDE];
  __shared__ __attribute__((aligned(16))) _Float16 Bs[128 * 32];

  const int tid  = threadIdx.x;
  const int lane = tid & 63;
  const int wv   = tid >> 6;
  const int wr   = wv >> 1;
  const int wc   = wv & 1;
  const int bm = blockIdx.x & 63;
  const int bn = blockIdx.x >> 6;
  const int m0 = bm * 128;
  const int n0 = bn * 128;

  const int a_m = tid >> 1;
  const int a_k = (tid & 1) << 4;
  const float* xptr = X    + (size_t)(m0 + a_m) * K_DIM + a_k;
  const int*   mptr = Mask + (size_t)(m0 + a_m) * K_DIM + a_k;
  _Float16* a_lds = &As[a_m * A_STRIDE + a_k];

  const int i0 = tid, i1 = tid + 256;
  const float* wp0 = W + (size_t)(n0 + (i0 >> 2)) * K_DIM + ((i0 & 3) << 3);
  const float* wp1 = W + (size_t)(n0 + (i1 >> 2)) * K_DIM + ((i1 & 3) << 3);
  _Float16* bl0 = &Bs[i0 * 8];
  _Float16* bl1 = &Bs[i1 * 8];

  f32x4 acc[4][4];
#pragma unroll
  for (int i = 0; i < 4; ++i)
#pragma unroll
    for (int j = 0; j < 4; ++j)
      acc[i][j] = (f32x4){0.f, 0.f, 0.f, 0.f};

  float4 xf0 = *(const float4*)(xptr +  0);
  float4 xf1 = *(const float4*)(xptr +  4);
  float4 xf2 = *(const float4*)(xptr +  8);
  float4 xf3 = *(const float4*)(xptr + 12);
  uint4  mr0 = *(const uint4*)(mptr +  0);
  uint4  mr1 = *(const uint4*)(mptr +  4);
  uint4  mr2 = *(const uint4*)(mptr +  8);
  uint4  mr3 = *(const uint4*)(mptr + 12);
  float4 wf0 = *(const float4*)(wp0 + 0);
  float4 wf1 = *(const float4*)(wp0 + 4);
  float4 wf2 = *(const float4*)(wp1 + 0);
  float4 wf3 = *(const float4*)(wp1 + 4);

#pragma unroll 1
  for (int kt = 0; kt < 128; ++kt) {
    {
      float xs[16] = {xf0.x, xf0.y, xf0.z, xf0.w, xf1.x, xf1.y, xf1.z, xf1.w,
                      xf2.x, xf2.y, xf2.z, xf2.w, xf3.x, xf3.y, xf3.z, xf3.w};
      u32 mk[16]   = {mr0.x, mr0.y, mr0.z, mr0.w, mr1.x, mr1.y, mr1.z, mr1.w,
                      mr2.x, mr2.y, mr2.z, mr2.w, mr3.x, mr3.y, mr3.z, mr3.w};
      u32 ow[8];
#pragma unroll
      for (int e = 0; e < 8; ++e)
        ow[e] = pack2(gelu_drop(xs[2 * e], mk[2 * e]), gelu_drop(xs[2 * e + 1], mk[2 * e + 1]));
      ((uint4*)a_lds)[0] = make_uint4(ow[0], ow[1], ow[2], ow[3]);
      ((uint4*)a_lds)[1] = make_uint4(ow[4], ow[5], ow[6], ow[7]);
    }
    {
      *(uint4*)bl0 = make_uint4(pack2(wf0.x, wf0.y), pack2(wf0.z, wf0.w),
                                pack2(wf1.x, wf1.y), pack2(wf1.z, wf1.w));
      *(uint4*)bl1 = make_uint4(pack2(wf2.x, wf2.y), pack2(wf2.z, wf2.w),
                                pack2(wf3.x, wf3.y), pack2(wf3.z, wf3.w));
    }
    __syncthreads();

    if (kt + 1 < 128) {
      xptr += 32; mptr += 32; wp0 += 32; wp1 += 32;
      xf0 = *(const float4*)(xptr +  0);
      xf1 = *(const float4*)(xptr +  4);
      xf2 = *(const float4*)(xptr +  8);
      xf3 = *(const float4*)(xptr + 12);
      mr0 = *(const uint4*)(mptr +  0);
      mr1 = *(const uint4*)(mptr +  4);
      mr2 = *(const uint4*)(mptr +  8);
      mr3 = *(const uint4*)(mptr + 12);
      wf0 = *(const float4*)(wp0 + 0);
      wf1 = *(const float4*)(wp0 + 4);
      wf2 = *(const float4*)(wp1 + 0);
      wf3 = *(const float4*)(wp1 + 4);
    }

    {
      const int fr2 = lane & 15;
      const int fk2 = (lane >> 4) << 3;
      half8 ar[4], br[4];
#pragma unroll
      for (int i = 0; i < 4; ++i)
        ar[i] = *(const half8*)&As[(wr * 64 + i * 16 + fr2) * A_STRIDE + fk2];
#pragma unroll
      for (int j = 0; j < 4; ++j)
        br[j] = *(const half8*)&Bs[(wc * 64 + j * 16 + fr2) * 32 + fk2];
#pragma unroll
      for (int i = 0; i < 4; ++i)
#pragma unroll
        for (int j = 0; j < 4; ++j)
          acc[i][j] = __builtin_amdgcn_mfma_f32_16x16x32_f16(ar[i], br[j], acc[i][j], 0, 0, 0);
    }
    __syncthreads();
  }

  const int fr = lane & 15;
  const int rq = (lane >> 4) << 2;
  float bv[4];
#pragma unroll
  for (int j = 0; j < 4; ++j)
    bv[j] = Bias[n0 + wc * 64 + j * 16 + fr];
#pragma unroll
  for (int i = 0; i < 4; ++i) {
    const int row0 = m0 + wr * 64 + i * 16 + rq;
#pragma unroll
    for (int j = 0; j < 4; ++j) {
      const int col = n0 + wc * 64 + j * 16 + fr;
#pragma unroll
      for (int r = 0; r < 4; ++r)
        Out[(size_t)(row0 + r) * N_DIM + col] = acc[i][j][r] + bv[j];
    }
  }
}

extern "C" void kernel_launch(void* const* d_in, const int* in_sizes, int n_in,
                              void* d_out, int out_size, void* d_ws, size_t ws_size,
                              hipStream_t stream) {
  const float* X    = (const float*)d_in[0];   // x (8192x4096), fp16 canonicalized to f32
  const float* W    = (const float*)d_in[1];   // weight (1024x4096) f32, K-contiguous
  const float* Bias = (const float*)d_in[2];   // bias (1024) f32
  const int*   Mk   = (const int*)d_in[3];     // keep-mask int32 0/1
  float* Out = (float*)d_out;                  // y (8192x1024) f32

  if (ws_size >= WS_NEEDED) {
    u16* H  = (u16*)d_ws;
    u16* Wt = (u16*)((char*)d_ws + H_BYTES);
    pack_kernel<<<WPACK_BLOCKS + PACKX_BLOCKS, 256, 0, stream>>>(X, Mk, W, H, Wt);
    gemm_kernel<<<(M_DIM / 128) * (N_DIM / 128), 256, 0, stream>>>(H, Wt, Bias, Out);  // 512 blocks
  } else {
    fused_fallback_kernel<<<64 * 8, 256, 0, stream>>>(X, W, Bias, Mk, Out);
  }
}